// Round 1
// baseline (442.031 us; speedup 1.0000x reference)
//
#include <hip/hip_runtime.h>
#include <hip/hip_bf16.h>

#define S_CNT 250
#define N_PED 200
#define MAXP  16
#define HID   512
#define BN    32

// d_ws layout: ws1 frags [pass8][ntl4][ks4][lane64] short8 = 131072 B
//              ws2 frags [pass8][kcl2][nt2][lane64] short8 =  32768 B
//              WaT [t16][k512] f32 (transposed W_attn)     =  32768 B
#define WS1_FRAGS 8192
#define WS2_FRAGS 2048
#define WAT_QUADS 2048
#define WS_NEED   196608u

typedef __attribute__((ext_vector_type(8))) short short8;
typedef __attribute__((ext_vector_type(4))) float floatx4;

__device__ __forceinline__ short f2bu(float f) {
    union { __hip_bfloat16 h; unsigned short u; } c;
    c.h = __float2bfloat16(f);
    return (short)c.u;
}

// ---- one-time weight convert + swizzle into workspace ----
__global__ __launch_bounds__(256) void cvt_kernel(
    const float* __restrict__ W1, const float* __restrict__ W2,
    const float* __restrict__ Wa,
    short8* __restrict__ ws1, short8* __restrict__ ws2,
    float* __restrict__ waT)
{
    int t = blockIdx.x * 256 + threadIdx.x;
    if (t < WS1_FRAGS) {
        int lane = t & 63, ks = (t >> 6) & 3, nt = (t >> 8) & 3, pass = t >> 10;
        int n  = pass * 64 + nt * 16 + (lane & 15);
        int k0 = ks * 32 + ((lane >> 4) << 3);
        short8 v;
#pragma unroll
        for (int j = 0; j < 8; ++j) v[j] = f2bu(W1[(k0 + j) * HID + n]);
        ws1[t] = v;
    } else if (t < WS1_FRAGS + WS2_FRAGS) {
        int t2 = t - WS1_FRAGS;
        int lane = t2 & 63, nt2 = (t2 >> 6) & 1, kcl = (t2 >> 7) & 1, pass = t2 >> 8;
        int kc = pass * 2 + kcl;
        int n  = nt2 * 16 + (lane & 15);
        int k0 = kc * 32 + ((lane >> 4) << 3);
        short8 v;
#pragma unroll
        for (int j = 0; j < 8; ++j) v[j] = f2bu(W2[(k0 + j) * BN + n]);
        ws2[t2] = v;
    } else if (t < WS1_FRAGS + WS2_FRAGS + WAT_QUADS) {
        // WaT[tt][k] = Wa[k][tt], stored f32, one dwordx4 per thread
        int t3 = t - (WS1_FRAGS + WS2_FRAGS);
        int tt = t3 >> 7;            // 0..15
        int k0 = (t3 & 127) << 2;    // 0..508 step 4
        floatx4 v;
#pragma unroll
        for (int j = 0; j < 4; ++j) v[j] = Wa[(k0 + j) * MAXP + tt];
        ((floatx4*)waT)[t3] = v;
    }
}

// Block = 4 waves, 8 peds (2/wave, same sequence). B-fragments stream DIRECTLY
// from pre-swizzled global (L1/L2-served, VMEM pipe) -> no fb LDS buffers, no
// main-loop barriers (X1c transpose is wave-private). B-frags hoisted across
// the 2 peds. r8-r12 lesson: 2-ped state can't fit 128 total regs -> stay at
// 2 blocks/CU (launch_bounds(256,2), no spill) and unload the LDS pipe instead.
// This round: (a) distances computed ONCE per ped into wave-private LDS
// (aliasing X2s, bitwise-identical arithmetic -> same selection), killing the
// 16x recompute + ~96 sqrt/lane; (b) logits via transposed-f32 WaT with
// dwordx4/b128 loads; (c) softmax fully in registers via shfl_xor (one __expf
// per lane, LG buffer removed).
__global__ __launch_bounds__(256, 2) void fused_pre(
    const float* __restrict__ h_states, const float* __restrict__ last_pos,
    const float* __restrict__ Wpos,     const float* __restrict__ bpos,
    const float* __restrict__ b1,       const float* __restrict__ b2,
    const float* __restrict__ WaT,      const float* __restrict__ ba,
    const short8* __restrict__ ws1,     const short8* __restrict__ ws2,
    float* __restrict__ out)
{
    __shared__ unsigned short X1c[4][2][16][42];   // per-wave, per-ped; pad 42
    __shared__ float X2s[4][512];                  // per-wave X2 [16][32]; also
                                                   // prologue dist scratch
    __shared__ float px[N_PED], py[N_PED];
    __shared__ float WS[4][16];                    // total ~20.2 KB

    const int tid = threadIdx.x;
    const int wv  = tid >> 6;
    const int ln  = tid & 63;
    const int q8  = (ln >> 4) << 3;
    const int c15 = ln & 15;
    const int s    = blockIdx.x / 25;
    const int base = s * N_PED;
    const int il0  = (blockIdx.x % 25) * 8 + wv * 2;

    if (tid < N_PED) {
        px[tid] = last_pos[(base + tid) * 2 + 0];
        py[tid] = last_pos[(base + tid) * 2 + 1];
    }
    __syncthreads();                               // the only block barrier

    // ---- per-ped selection (distances computed once, wave-private LDS) ----
    float* dbuf = (float*)&X2s[wv][0];             // 200 floats of scratch
    short8  af[2][4];
    floatx4 c2[2][2] = {};
    for (int pedi = 0; pedi < 2; ++pedi) {
        const int il = il0 + pedi;
        const float xi = px[il], yi = py[il];
        // cooperative distance fill: identical arithmetic to the old per-lane
        // recompute -> bitwise-identical d values -> identical selection
#pragma unroll
        for (int j0 = 0; j0 < 256; j0 += 64) {
            int j = j0 + ln;
            if (j < N_PED) {
                float dx = __fsub_rn(px[j], xi), dy = __fsub_rn(py[j], yi);
                dbuf[j] = __fsqrt_rn(__builtin_fmaf(dx, dx, __fmul_rn(dy, dy)));
            }
        }
        __builtin_amdgcn_wave_barrier();           // keep fill before compares
        const int mm = c15, qq = ln >> 4;
        const float dm = dbuf[mm];
        int cnt = 0;
        // quarter ranges 48/48/48/56 so every b128 read is 16B-aligned
        const int jbeg = qq * 48;
        const int jend = (qq == 3) ? N_PED : (jbeg + 48);
        for (int j = jbeg; j < jend; j += 4) {
            floatx4 d4 = *(const floatx4*)&dbuf[j];
#pragma unroll
            for (int e = 0; e < 4; ++e)
                cnt += (d4[e] < dm || (d4[e] == dm && (j + e) < mm)) ? 1 : 0;
        }
        cnt += __shfl_xor(cnt, 16, 64);
        cnt += __shfl_xor(cnt, 32, 64);            // lane ln holds rank(ln&15)
        const int sm = cnt;
#pragma unroll
        for (int ks = 0; ks < 2; ++ks) {           // k 0..63: h_sel
            const float* hp = &h_states[(base + sm) * 64 + ks * 32 + q8];
            short8 v;
#pragma unroll
            for (int j = 0; j < 8; ++j) v[j] = f2bu(hp[j]);
            af[pedi][ks] = v;
        }
        const float fx = px[sm] - xi, fy = py[sm] - yi;
#pragma unroll
        for (int ks = 2; ks < 4; ++ks) {           // k 64..127: pos embedding
            int e0 = (ks - 2) * 32 + q8;
            short8 v;
#pragma unroll
            for (int j = 0; j < 8; ++j) {
                float e = fx * Wpos[e0 + j] + fy * Wpos[64 + e0 + j] + bpos[e0 + j];
                v[j] = f2bu(e);
            }
            af[pedi][ks] = v;
        }
    }

    // ---- main loop: 8 passes x 4 n-tiles, no barriers ----
    for (int p = 0; p < 8; ++p) {
#pragma unroll
        for (int ntl = 0; ntl < 4; ++ntl) {
            const int nt = p * 4 + ntl;
            short8 bf[4];                          // B-frags, shared by both peds
#pragma unroll
            for (int ks = 0; ks < 4; ++ks)
                bf[ks] = ws1[p * 1024 + ntl * 256 + ks * 64 + ln];
            const float bb = b1[nt * 16 + c15];
            const int colb = (ntl & 1) * 16 + c15;
#pragma unroll
            for (int pedi = 0; pedi < 2; ++pedi) {
                floatx4 c = {};
#pragma unroll
                for (int ks = 0; ks < 4; ++ks)
                    c = __builtin_amdgcn_mfma_f32_16x16x32_bf16(
                            af[pedi][ks], bf[ks], c, 0, 0, 0);
                // C layout: col = ln&15, row = (ln>>4)*4 + r
#pragma unroll
                for (int r = 0; r < 4; ++r)
                    X1c[wv][pedi][(ln >> 4) * 4 + r][colb] =
                        (unsigned short)f2bu(fmaxf(c[r] + bb, 0.f));
            }
            if (ntl & 1) {                         // 32-col X1 chunks ready
                const int kcl = ntl >> 1;
                short8 w20 = ws2[p * 256 + kcl * 128 + ln];
                short8 w21 = ws2[p * 256 + kcl * 128 + 64 + ln];
#pragma unroll
                for (int pedi = 0; pedi < 2; ++pedi) {
                    short8 a2 = *(const short8*)&X1c[wv][pedi][c15][q8];
                    c2[pedi][0] = __builtin_amdgcn_mfma_f32_16x16x32_bf16(
                            a2, w20, c2[pedi][0], 0, 0, 0);
                    c2[pedi][1] = __builtin_amdgcn_mfma_f32_16x16x32_bf16(
                            a2, w21, c2[pedi][1], 0, 0, 0);
                }
            }
        }
    }

    // ---- epilogue per ped (wave-private LDS; vectorized logits, reg softmax)
    for (int pedi = 0; pedi < 2; ++pedi) {
#pragma unroll
        for (int nt2 = 0; nt2 < 2; ++nt2) {
            const float bb2 = b2[nt2 * 16 + c15];
#pragma unroll
            for (int r = 0; r < 4; ++r)
                X2s[wv][((ln >> 4) * 4 + r) * 32 + nt2 * 16 + c15] =
                    fmaxf(c2[pedi][nt2][r] + bb2, 0.f);
        }
        float lg;
        {
            const int t = c15, g = ln >> 4;
            const float* xr = &X2s[wv][g * 128];       // b128 broadcast reads
            const float* wr = WaT + t * 512 + g * 128; // contiguous dwordx4
            lg = 0.f;
#pragma unroll 8
            for (int kk = 0; kk < 128; kk += 4) {
                floatx4 xv = *(const floatx4*)(xr + kk);
                floatx4 w4 = *(const floatx4*)(wr + kk);
                lg = __builtin_fmaf(xv[0], w4[0],
                     __builtin_fmaf(xv[1], w4[1],
                     __builtin_fmaf(xv[2], w4[2],
                     __builtin_fmaf(xv[3], w4[3], lg))));
            }
            lg += __shfl_xor(lg, 16, 64);
            lg += __shfl_xor(lg, 32, 64);   // every lane: logit for t = c15
        }
        // softmax over the 16 t's, fully in registers (one __expf per lane)
        const float lgf = lg + ba[c15];
        float mxv = lgf;
        mxv = fmaxf(mxv, __shfl_xor(mxv, 1, 64));
        mxv = fmaxf(mxv, __shfl_xor(mxv, 2, 64));
        mxv = fmaxf(mxv, __shfl_xor(mxv, 4, 64));
        mxv = fmaxf(mxv, __shfl_xor(mxv, 8, 64));
        const float ev = __expf(lgf - mxv);
        float se = ev;
        se += __shfl_xor(se, 1, 64);
        se += __shfl_xor(se, 2, 64);
        se += __shfl_xor(se, 4, 64);
        se += __shfl_xor(se, 8, 64);
        if (ln < 16) WS[wv][ln] = ev / se;
        if (ln < BN) {
            float o = 0.f;
#pragma unroll
            for (int m = 0; m < MAXP; ++m) o += WS[wv][m] * X2s[wv][m * BN + ln];
            out[(base + il0 + pedi) * BN + ln] = o;
        }
    }
}

// Fallback (ws too small): r11-verified LDS-staging version, inline cvt.
__global__ __launch_bounds__(256, 2) void fused_fb(
    const float* __restrict__ h_states, const float* __restrict__ last_pos,
    const float* __restrict__ Wpos,     const float* __restrict__ bpos,
    const float* __restrict__ W1,       const float* __restrict__ b1,
    const float* __restrict__ W2,       const float* __restrict__ b2,
    const float* __restrict__ Wa,       const float* __restrict__ ba,
    float* __restrict__ out)
{
    __shared__ short8 fb1[1024];
    __shared__ short8 fb2[256];
    __shared__ unsigned short X1c[4][16][40];
    __shared__ float X2s[4][512];
    __shared__ float px[N_PED], py[N_PED];
    __shared__ float LG[4][16], WS[4][16];

    const int tid = threadIdx.x;
    const int wv  = tid >> 6;
    const int ln  = tid & 63;
    const int q8  = (ln >> 4) << 3;
    const int c15 = ln & 15;
    const int s    = blockIdx.x / 25;
    const int base = s * N_PED;
    const int il0  = (blockIdx.x % 25) * 8 + wv * 2;

    if (tid < N_PED) {
        px[tid] = last_pos[(base + tid) * 2 + 0];
        py[tid] = last_pos[(base + tid) * 2 + 1];
    }
    __syncthreads();

    short8  af[2][4];
    floatx4 c2[2][2] = {};
    for (int pedi = 0; pedi < 2; ++pedi) {
        const int il = il0 + pedi;
        const float xi = px[il], yi = py[il];
        const int mm = c15, qq = ln >> 4;
        int cnt;
        {
            float dxm = __fsub_rn(px[mm], xi), dym = __fsub_rn(py[mm], yi);
            float dm = __fsqrt_rn(__builtin_fmaf(dxm, dxm, __fmul_rn(dym, dym)));
            cnt = 0;
            for (int j = qq * 50; j < qq * 50 + 50; ++j) {
                float dx = __fsub_rn(px[j], xi), dy = __fsub_rn(py[j], yi);
                float dj = __fsqrt_rn(__builtin_fmaf(dx, dx, __fmul_rn(dy, dy)));
                cnt += (dj < dm || (dj == dm && j < mm)) ? 1 : 0;
            }
            cnt += __shfl_xor(cnt, 16, 64);
            cnt += __shfl_xor(cnt, 32, 64);
        }
        const int sm = cnt;
#pragma unroll
        for (int ks = 0; ks < 2; ++ks) {
            const float* hp = &h_states[(base + sm) * 64 + ks * 32 + q8];
            short8 v;
#pragma unroll
            for (int j = 0; j < 8; ++j) v[j] = f2bu(hp[j]);
            af[pedi][ks] = v;
        }
        const float fx = px[sm] - xi, fy = py[sm] - yi;
#pragma unroll
        for (int ks = 2; ks < 4; ++ks) {
            int e0 = (ks - 2) * 32 + q8;
            short8 v;
#pragma unroll
            for (int j = 0; j < 8; ++j) {
                float e = fx * Wpos[e0 + j] + fy * Wpos[64 + e0 + j] + bpos[e0 + j];
                v[j] = f2bu(e);
            }
            af[pedi][ks] = v;
        }
    }

    for (int p = 0; p < 8; ++p) {
        __syncthreads();
        for (int f = tid; f < 1024; f += 256) {
            int lane = f & 63, ks = (f >> 6) & 3, nt = f >> 8;
            int n  = p * 64 + nt * 16 + (lane & 15);
            int k0 = ks * 32 + ((lane >> 4) << 3);
            short8 v;
#pragma unroll
            for (int j = 0; j < 8; ++j) v[j] = f2bu(W1[(k0 + j) * HID + n]);
            fb1[f] = v;
        }
        {
            int lane = tid & 63, nt2 = (tid >> 6) & 1, kcl = tid >> 7;
            int kc = p * 2 + kcl;
            int n  = nt2 * 16 + (lane & 15);
            int k0 = kc * 32 + ((lane >> 4) << 3);
            short8 v;
#pragma unroll
            for (int j = 0; j < 8; ++j) v[j] = f2bu(W2[(k0 + j) * BN + n]);
            fb2[tid] = v;
        }
        __syncthreads();
#pragma unroll
        for (int pedi = 0; pedi < 2; ++pedi) {
#pragma unroll
            for (int ntl = 0; ntl < 4; ++ntl) {
                const int nt = p * 4 + ntl;
                floatx4 c = {};
#pragma unroll
                for (int ks = 0; ks < 4; ++ks)
                    c = __builtin_amdgcn_mfma_f32_16x16x32_bf16(
                            af[pedi][ks], fb1[ntl * 256 + ks * 64 + ln], c, 0, 0, 0);
                const float bb = b1[nt * 16 + c15];
                const int colb = (ntl & 1) * 16 + c15;
#pragma unroll
                for (int r = 0; r < 4; ++r)
                    X1c[wv][(ln >> 4) * 4 + r][colb] =
                        (unsigned short)f2bu(fmaxf(c[r] + bb, 0.f));
                if (ntl & 1) {
                    const int kcl = ntl >> 1;
                    short8 a2 = *(const short8*)&X1c[wv][c15][q8];
                    c2[pedi][0] = __builtin_amdgcn_mfma_f32_16x16x32_bf16(
                            a2, fb2[kcl * 128 + ln], c2[pedi][0], 0, 0, 0);
                    c2[pedi][1] = __builtin_amdgcn_mfma_f32_16x16x32_bf16(
                            a2, fb2[kcl * 128 + 64 + ln], c2[pedi][1], 0, 0, 0);
                }
            }
        }
    }

    for (int pedi = 0; pedi < 2; ++pedi) {
#pragma unroll
        for (int nt2 = 0; nt2 < 2; ++nt2) {
            const float bb2 = b2[nt2 * 16 + c15];
#pragma unroll
            for (int r = 0; r < 4; ++r)
                X2s[wv][((ln >> 4) * 4 + r) * 32 + nt2 * 16 + c15] =
                    fmaxf(c2[pedi][nt2][r] + bb2, 0.f);
        }
        {
            int t = c15, g = ln >> 4;
            float lg = 0.f;
            for (int k = g * 128; k < g * 128 + 128; ++k)
                lg += X2s[wv][k] * Wa[k * MAXP + t];
            lg += __shfl_xor(lg, 16, 64);
            lg += __shfl_xor(lg, 32, 64);
            if (ln < 16) LG[wv][ln] = lg + ba[ln];
        }
        float mx = -1e30f;
#pragma unroll
        for (int m = 0; m < MAXP; ++m) mx = fmaxf(mx, LG[wv][m]);
        float sum = 0.f;
#pragma unroll
        for (int m = 0; m < MAXP; ++m) sum += expf(LG[wv][m] - mx);
        if (ln < 16) WS[wv][ln] = expf(LG[wv][ln] - mx) / sum;
        if (ln < BN) {
            float o = 0.f;
#pragma unroll
            for (int m = 0; m < MAXP; ++m) o += WS[wv][m] * X2s[wv][m * BN + ln];
            out[(base + il0 + pedi) * BN + ln] = o;
        }
    }
}

extern "C" void kernel_launch(void* const* d_in, const int* in_sizes, int n_in,
                              void* d_out, int out_size, void* d_ws, size_t ws_size,
                              hipStream_t stream) {
    const float* h_states = (const float*)d_in[0];
    const float* last_pos = (const float*)d_in[1];
    const float* Wpos     = (const float*)d_in[2];
    const float* bpos     = (const float*)d_in[3];
    const float* W1       = (const float*)d_in[4];
    const float* b1       = (const float*)d_in[5];
    const float* W2       = (const float*)d_in[6];
    const float* b2       = (const float*)d_in[7];
    const float* Wa       = (const float*)d_in[8];
    const float* ba       = (const float*)d_in[9];
    // d_in[10] seq_start_end, d_in[11] train_or_test: structurally constant, unused

    short8* ws1 = (short8*)d_ws;
    short8* ws2 = ws1 + WS1_FRAGS;
    float*  waT = (float*)(ws2 + WS2_FRAGS);
    const int grid = (S_CNT * N_PED) / 8;          // 6250

    if (ws_size >= WS_NEED) {
        cvt_kernel<<<48, 256, 0, stream>>>(W1, W2, Wa, ws1, ws2, waT);
        fused_pre<<<grid, 256, 0, stream>>>(
            h_states, last_pos, Wpos, bpos, b1, b2, waT, ba, ws1, ws2, (float*)d_out);
    } else {
        fused_fb<<<grid, 256, 0, stream>>>(
            h_states, last_pos, Wpos, bpos, W1, b1, W2, b2, Wa, ba, (float*)d_out);
    }
}

// Round 2
// 414.666 us; speedup vs baseline: 1.0660x; 1.0660x over previous
//
#include <hip/hip_runtime.h>
#include <hip/hip_bf16.h>

#define S_CNT 250
#define N_PED 200
#define MAXP  16
#define HID   512
#define BN    32

// d_ws layout: ws1 frags [pass8][ntl4][ks4][lane64] short8 = 131072 B
//              ws2 frags [pass8][kcl2][nt2][lane64] short8 =  32768 B
//              WaT [t16][k512] f32 (transposed W_attn)     =  32768 B
#define WS1_FRAGS 8192
#define WS2_FRAGS 2048
#define WAT_QUADS 2048
#define WS_NEED   196608u

typedef __attribute__((ext_vector_type(8))) short short8;
typedef __attribute__((ext_vector_type(4))) float floatx4;

__device__ __forceinline__ short f2bu(float f) {
    union { __hip_bfloat16 h; unsigned short u; } c;
    c.h = __float2bfloat16(f);
    return (short)c.u;
}

// ---- one-time weight convert + swizzle into workspace ----
__global__ __launch_bounds__(256) void cvt_kernel(
    const float* __restrict__ W1, const float* __restrict__ W2,
    const float* __restrict__ Wa,
    short8* __restrict__ ws1, short8* __restrict__ ws2,
    float* __restrict__ waT)
{
    int t = blockIdx.x * 256 + threadIdx.x;
    if (t < WS1_FRAGS) {
        int lane = t & 63, ks = (t >> 6) & 3, nt = (t >> 8) & 3, pass = t >> 10;
        int n  = pass * 64 + nt * 16 + (lane & 15);
        int k0 = ks * 32 + ((lane >> 4) << 3);
        short8 v;
#pragma unroll
        for (int j = 0; j < 8; ++j) v[j] = f2bu(W1[(k0 + j) * HID + n]);
        ws1[t] = v;
    } else if (t < WS1_FRAGS + WS2_FRAGS) {
        int t2 = t - WS1_FRAGS;
        int lane = t2 & 63, nt2 = (t2 >> 6) & 1, kcl = (t2 >> 7) & 1, pass = t2 >> 8;
        int kc = pass * 2 + kcl;
        int n  = nt2 * 16 + (lane & 15);
        int k0 = kc * 32 + ((lane >> 4) << 3);
        short8 v;
#pragma unroll
        for (int j = 0; j < 8; ++j) v[j] = f2bu(W2[(k0 + j) * BN + n]);
        ws2[t2] = v;
    } else if (t < WS1_FRAGS + WS2_FRAGS + WAT_QUADS) {
        // WaT[tt][k] = Wa[k][tt], stored f32, one dwordx4 per thread
        int t3 = t - (WS1_FRAGS + WS2_FRAGS);
        int tt = t3 >> 7;            // 0..15
        int k0 = (t3 & 127) << 2;    // 0..508 step 4
        floatx4 v;
#pragma unroll
        for (int j = 0; j < 4; ++j) v[j] = Wa[(k0 + j) * MAXP + tt];
        ((floatx4*)waT)[t3] = v;
    }
}

// Block = 4 waves, 8 peds (2/wave, same sequence). B-fragments stream DIRECTLY
// from pre-swizzled global (L1/L2-served, VMEM pipe) -> no fb LDS buffers, no
// main-loop barriers (X1c transpose is wave-private). B-frags hoisted across
// the 2 peds. r8-r12 lesson: 2-ped state can't fit 128 total regs -> stay at
// 2 blocks/CU (launch_bounds(256,2), no spill) and unload the LDS pipe instead.
// Round-1 lesson: do NOT replace the per-lane selection recompute with a
// cooperative LDS distance buffer — the recompute's "redundancy" is free
// (SIMD-parallel, same issue count), while the LDS version adds a serial
// ds_write->waitcnt->ds_read chain per ped that can't be hidden at 2-3
// blocks/CU (280us -> 406us regression). Selection kept bitwise-identical
// to the verified round-0 version.
// Kept from round 1 (pure work removal, no new hazards):
//   (b) logits via transposed-f32 WaT: contiguous dwordx4 per lane instead
//       of 128 scalar gathers; X2s read as b128 broadcasts.
//   (c) softmax fully in registers via shfl_xor: one __expf per lane
//       replaces 2x16 libm expf + LDS LG round-trip.
__global__ __launch_bounds__(256, 2) void fused_pre(
    const float* __restrict__ h_states, const float* __restrict__ last_pos,
    const float* __restrict__ Wpos,     const float* __restrict__ bpos,
    const float* __restrict__ b1,       const float* __restrict__ b2,
    const float* __restrict__ WaT,      const float* __restrict__ ba,
    const short8* __restrict__ ws1,     const short8* __restrict__ ws2,
    float* __restrict__ out)
{
    __shared__ unsigned short X1c[4][2][16][42];   // per-wave, per-ped; pad 42
    __shared__ float X2s[4][512];                  // per-wave X2 [16][32]
    __shared__ float px[N_PED], py[N_PED];
    __shared__ float WS[4][16];                    // total ~20.2 KB

    const int tid = threadIdx.x;
    const int wv  = tid >> 6;
    const int ln  = tid & 63;
    const int q8  = (ln >> 4) << 3;
    const int c15 = ln & 15;
    const int s    = blockIdx.x / 25;
    const int base = s * N_PED;
    const int il0  = (blockIdx.x % 25) * 8 + wv * 2;

    if (tid < N_PED) {
        px[tid] = last_pos[(base + tid) * 2 + 0];
        py[tid] = last_pos[(base + tid) * 2 + 1];
    }
    __syncthreads();                               // the only block barrier

    // ---- per-ped selection (r8-verified, round-0 bitwise) + A-frag build ----
    short8  af[2][4];
    floatx4 c2[2][2] = {};
    for (int pedi = 0; pedi < 2; ++pedi) {
        const int il = il0 + pedi;
        const float xi = px[il], yi = py[il];
        const int mm = c15, qq = ln >> 4;
        int cnt;
        {
            float dxm = __fsub_rn(px[mm], xi), dym = __fsub_rn(py[mm], yi);
            float dm = __fsqrt_rn(__builtin_fmaf(dxm, dxm, __fmul_rn(dym, dym)));
            cnt = 0;
            for (int j = qq * 50; j < qq * 50 + 50; ++j) {
                float dx = __fsub_rn(px[j], xi), dy = __fsub_rn(py[j], yi);
                float dj = __fsqrt_rn(__builtin_fmaf(dx, dx, __fmul_rn(dy, dy)));
                cnt += (dj < dm || (dj == dm && j < mm)) ? 1 : 0;
            }
            cnt += __shfl_xor(cnt, 16, 64);
            cnt += __shfl_xor(cnt, 32, 64);        // lane ln holds rank(ln&15)
        }
        const int sm = cnt;
#pragma unroll
        for (int ks = 0; ks < 2; ++ks) {           // k 0..63: h_sel
            const float* hp = &h_states[(base + sm) * 64 + ks * 32 + q8];
            short8 v;
#pragma unroll
            for (int j = 0; j < 8; ++j) v[j] = f2bu(hp[j]);
            af[pedi][ks] = v;
        }
        const float fx = px[sm] - xi, fy = py[sm] - yi;
#pragma unroll
        for (int ks = 2; ks < 4; ++ks) {           // k 64..127: pos embedding
            int e0 = (ks - 2) * 32 + q8;
            short8 v;
#pragma unroll
            for (int j = 0; j < 8; ++j) {
                float e = fx * Wpos[e0 + j] + fy * Wpos[64 + e0 + j] + bpos[e0 + j];
                v[j] = f2bu(e);
            }
            af[pedi][ks] = v;
        }
    }

    // ---- main loop: 8 passes x 4 n-tiles, no barriers ----
    for (int p = 0; p < 8; ++p) {
#pragma unroll
        for (int ntl = 0; ntl < 4; ++ntl) {
            const int nt = p * 4 + ntl;
            short8 bf[4];                          // B-frags, shared by both peds
#pragma unroll
            for (int ks = 0; ks < 4; ++ks)
                bf[ks] = ws1[p * 1024 + ntl * 256 + ks * 64 + ln];
            const float bb = b1[nt * 16 + c15];
            const int colb = (ntl & 1) * 16 + c15;
#pragma unroll
            for (int pedi = 0; pedi < 2; ++pedi) {
                floatx4 c = {};
#pragma unroll
                for (int ks = 0; ks < 4; ++ks)
                    c = __builtin_amdgcn_mfma_f32_16x16x32_bf16(
                            af[pedi][ks], bf[ks], c, 0, 0, 0);
                // C layout: col = ln&15, row = (ln>>4)*4 + r
#pragma unroll
                for (int r = 0; r < 4; ++r)
                    X1c[wv][pedi][(ln >> 4) * 4 + r][colb] =
                        (unsigned short)f2bu(fmaxf(c[r] + bb, 0.f));
            }
            if (ntl & 1) {                         // 32-col X1 chunks ready
                const int kcl = ntl >> 1;
                short8 w20 = ws2[p * 256 + kcl * 128 + ln];
                short8 w21 = ws2[p * 256 + kcl * 128 + 64 + ln];
#pragma unroll
                for (int pedi = 0; pedi < 2; ++pedi) {
                    short8 a2 = *(const short8*)&X1c[wv][pedi][c15][q8];
                    c2[pedi][0] = __builtin_amdgcn_mfma_f32_16x16x32_bf16(
                            a2, w20, c2[pedi][0], 0, 0, 0);
                    c2[pedi][1] = __builtin_amdgcn_mfma_f32_16x16x32_bf16(
                            a2, w21, c2[pedi][1], 0, 0, 0);
                }
            }
        }
    }

    // ---- epilogue per ped (wave-private LDS; vectorized logits, reg softmax)
    for (int pedi = 0; pedi < 2; ++pedi) {
#pragma unroll
        for (int nt2 = 0; nt2 < 2; ++nt2) {
            const float bb2 = b2[nt2 * 16 + c15];
#pragma unroll
            for (int r = 0; r < 4; ++r)
                X2s[wv][((ln >> 4) * 4 + r) * 32 + nt2 * 16 + c15] =
                    fmaxf(c2[pedi][nt2][r] + bb2, 0.f);
        }
        float lg;
        {
            const int t = c15, g = ln >> 4;
            const float* xr = &X2s[wv][g * 128];       // b128 broadcast reads
            const float* wr = WaT + t * 512 + g * 128; // contiguous dwordx4
            lg = 0.f;
#pragma unroll 8
            for (int kk = 0; kk < 128; kk += 4) {
                floatx4 xv = *(const floatx4*)(xr + kk);
                floatx4 w4 = *(const floatx4*)(wr + kk);
                lg = __builtin_fmaf(xv[0], w4[0],
                     __builtin_fmaf(xv[1], w4[1],
                     __builtin_fmaf(xv[2], w4[2],
                     __builtin_fmaf(xv[3], w4[3], lg))));
            }
            lg += __shfl_xor(lg, 16, 64);
            lg += __shfl_xor(lg, 32, 64);   // every lane: logit for t = c15
        }
        // softmax over the 16 t's, fully in registers (one __expf per lane)
        const float lgf = lg + ba[c15];
        float mxv = lgf;
        mxv = fmaxf(mxv, __shfl_xor(mxv, 1, 64));
        mxv = fmaxf(mxv, __shfl_xor(mxv, 2, 64));
        mxv = fmaxf(mxv, __shfl_xor(mxv, 4, 64));
        mxv = fmaxf(mxv, __shfl_xor(mxv, 8, 64));
        const float ev = __expf(lgf - mxv);
        float se = ev;
        se += __shfl_xor(se, 1, 64);
        se += __shfl_xor(se, 2, 64);
        se += __shfl_xor(se, 4, 64);
        se += __shfl_xor(se, 8, 64);
        if (ln < 16) WS[wv][ln] = ev / se;
        if (ln < BN) {
            float o = 0.f;
#pragma unroll
            for (int m = 0; m < MAXP; ++m) o += WS[wv][m] * X2s[wv][m * BN + ln];
            out[(base + il0 + pedi) * BN + ln] = o;
        }
    }
}

// Fallback (ws too small): r11-verified LDS-staging version, inline cvt.
__global__ __launch_bounds__(256, 2) void fused_fb(
    const float* __restrict__ h_states, const float* __restrict__ last_pos,
    const float* __restrict__ Wpos,     const float* __restrict__ bpos,
    const float* __restrict__ W1,       const float* __restrict__ b1,
    const float* __restrict__ W2,       const float* __restrict__ b2,
    const float* __restrict__ Wa,       const float* __restrict__ ba,
    float* __restrict__ out)
{
    __shared__ short8 fb1[1024];
    __shared__ short8 fb2[256];
    __shared__ unsigned short X1c[4][16][40];
    __shared__ float X2s[4][512];
    __shared__ float px[N_PED], py[N_PED];
    __shared__ float LG[4][16], WS[4][16];

    const int tid = threadIdx.x;
    const int wv  = tid >> 6;
    const int ln  = tid & 63;
    const int q8  = (ln >> 4) << 3;
    const int c15 = ln & 15;
    const int s    = blockIdx.x / 25;
    const int base = s * N_PED;
    const int il0  = (blockIdx.x % 25) * 8 + wv * 2;

    if (tid < N_PED) {
        px[tid] = last_pos[(base + tid) * 2 + 0];
        py[tid] = last_pos[(base + tid) * 2 + 1];
    }
    __syncthreads();

    short8  af[2][4];
    floatx4 c2[2][2] = {};
    for (int pedi = 0; pedi < 2; ++pedi) {
        const int il = il0 + pedi;
        const float xi = px[il], yi = py[il];
        const int mm = c15, qq = ln >> 4;
        int cnt;
        {
            float dxm = __fsub_rn(px[mm], xi), dym = __fsub_rn(py[mm], yi);
            float dm = __fsqrt_rn(__builtin_fmaf(dxm, dxm, __fmul_rn(dym, dym)));
            cnt = 0;
            for (int j = qq * 50; j < qq * 50 + 50; ++j) {
                float dx = __fsub_rn(px[j], xi), dy = __fsub_rn(py[j], yi);
                float dj = __fsqrt_rn(__builtin_fmaf(dx, dx, __fmul_rn(dy, dy)));
                cnt += (dj < dm || (dj == dm && j < mm)) ? 1 : 0;
            }
            cnt += __shfl_xor(cnt, 16, 64);
            cnt += __shfl_xor(cnt, 32, 64);
        }
        const int sm = cnt;
#pragma unroll
        for (int ks = 0; ks < 2; ++ks) {
            const float* hp = &h_states[(base + sm) * 64 + ks * 32 + q8];
            short8 v;
#pragma unroll
            for (int j = 0; j < 8; ++j) v[j] = f2bu(hp[j]);
            af[pedi][ks] = v;
        }
        const float fx = px[sm] - xi, fy = py[sm] - yi;
#pragma unroll
        for (int ks = 2; ks < 4; ++ks) {
            int e0 = (ks - 2) * 32 + q8;
            short8 v;
#pragma unroll
            for (int j = 0; j < 8; ++j) {
                float e = fx * Wpos[e0 + j] + fy * Wpos[64 + e0 + j] + bpos[e0 + j];
                v[j] = f2bu(e);
            }
            af[pedi][ks] = v;
        }
    }

    for (int p = 0; p < 8; ++p) {
        __syncthreads();
        for (int f = tid; f < 1024; f += 256) {
            int lane = f & 63, ks = (f >> 6) & 3, nt = f >> 8;
            int n  = p * 64 + nt * 16 + (lane & 15);
            int k0 = ks * 32 + ((lane >> 4) << 3);
            short8 v;
#pragma unroll
            for (int j = 0; j < 8; ++j) v[j] = f2bu(W1[(k0 + j) * HID + n]);
            fb1[f] = v;
        }
        {
            int lane = tid & 63, nt2 = (tid >> 6) & 1, kcl = tid >> 7;
            int kc = p * 2 + kcl;
            int n  = nt2 * 16 + (lane & 15);
            int k0 = kc * 32 + ((lane >> 4) << 3);
            short8 v;
#pragma unroll
            for (int j = 0; j < 8; ++j) v[j] = f2bu(W2[(k0 + j) * BN + n]);
            fb2[tid] = v;
        }
        __syncthreads();
#pragma unroll
        for (int pedi = 0; pedi < 2; ++pedi) {
#pragma unroll
            for (int ntl = 0; ntl < 4; ++ntl) {
                const int nt = p * 4 + ntl;
                floatx4 c = {};
#pragma unroll
                for (int ks = 0; ks < 4; ++ks)
                    c = __builtin_amdgcn_mfma_f32_16x16x32_bf16(
                            af[pedi][ks], fb1[ntl * 256 + ks * 64 + ln], c, 0, 0, 0);
                const float bb = b1[nt * 16 + c15];
                const int colb = (ntl & 1) * 16 + c15;
#pragma unroll
                for (int r = 0; r < 4; ++r)
                    X1c[wv][(ln >> 4) * 4 + r][colb] =
                        (unsigned short)f2bu(fmaxf(c[r] + bb, 0.f));
                if (ntl & 1) {
                    const int kcl = ntl >> 1;
                    short8 a2 = *(const short8*)&X1c[wv][c15][q8];
                    c2[pedi][0] = __builtin_amdgcn_mfma_f32_16x16x32_bf16(
                            a2, fb2[kcl * 128 + ln], c2[pedi][0], 0, 0, 0);
                    c2[pedi][1] = __builtin_amdgcn_mfma_f32_16x16x32_bf16(
                            a2, fb2[kcl * 128 + 64 + ln], c2[pedi][1], 0, 0, 0);
                }
            }
        }
    }

    for (int pedi = 0; pedi < 2; ++pedi) {
#pragma unroll
        for (int nt2 = 0; nt2 < 2; ++nt2) {
            const float bb2 = b2[nt2 * 16 + c15];
#pragma unroll
            for (int r = 0; r < 4; ++r)
                X2s[wv][((ln >> 4) * 4 + r) * 32 + nt2 * 16 + c15] =
                    fmaxf(c2[pedi][nt2][r] + bb2, 0.f);
        }
        {
            int t = c15, g = ln >> 4;
            float lg = 0.f;
            for (int k = g * 128; k < g * 128 + 128; ++k)
                lg += X2s[wv][k] * Wa[k * MAXP + t];
            lg += __shfl_xor(lg, 16, 64);
            lg += __shfl_xor(lg, 32, 64);
            if (ln < 16) LG[wv][ln] = lg + ba[ln];
        }
        float mx = -1e30f;
#pragma unroll
        for (int m = 0; m < MAXP; ++m) mx = fmaxf(mx, LG[wv][m]);
        float sum = 0.f;
#pragma unroll
        for (int m = 0; m < MAXP; ++m) sum += expf(LG[wv][m] - mx);
        if (ln < 16) WS[wv][ln] = expf(LG[wv][ln] - mx) / sum;
        if (ln < BN) {
            float o = 0.f;
#pragma unroll
            for (int m = 0; m < MAXP; ++m) o += WS[wv][m] * X2s[wv][m * BN + ln];
            out[(base + il0 + pedi) * BN + ln] = o;
        }
    }
}

extern "C" void kernel_launch(void* const* d_in, const int* in_sizes, int n_in,
                              void* d_out, int out_size, void* d_ws, size_t ws_size,
                              hipStream_t stream) {
    const float* h_states = (const float*)d_in[0];
    const float* last_pos = (const float*)d_in[1];
    const float* Wpos     = (const float*)d_in[2];
    const float* bpos     = (const float*)d_in[3];
    const float* W1       = (const float*)d_in[4];
    const float* b1       = (const float*)d_in[5];
    const float* W2       = (const float*)d_in[6];
    const float* b2       = (const float*)d_in[7];
    const float* Wa       = (const float*)d_in[8];
    const float* ba       = (const float*)d_in[9];
    // d_in[10] seq_start_end, d_in[11] train_or_test: structurally constant, unused

    short8* ws1 = (short8*)d_ws;
    short8* ws2 = ws1 + WS1_FRAGS;
    float*  waT = (float*)(ws2 + WS2_FRAGS);
    const int grid = (S_CNT * N_PED) / 8;          // 6250

    if (ws_size >= WS_NEED) {
        cvt_kernel<<<48, 256, 0, stream>>>(W1, W2, Wa, ws1, ws2, waT);
        fused_pre<<<grid, 256, 0, stream>>>(
            h_states, last_pos, Wpos, bpos, b1, b2, waT, ba, ws1, ws2, (float*)d_out);
    } else {
        fused_fb<<<grid, 256, 0, stream>>>(
            h_states, last_pos, Wpos, bpos, W1, b1, W2, b2, Wa, ba, (float*)d_out);
    }
}

// Round 3
// 314.903 us; speedup vs baseline: 1.4037x; 1.3168x over previous
//
#include <hip/hip_runtime.h>
#include <hip/hip_bf16.h>

#define S_CNT 250
#define N_PED 200
#define MAXP  16
#define HID   512
#define BN    32

// d_ws layout: ws1 frags [pass8][ntl4][ks4][lane64] short8 = 131072 B
//              ws2 frags [pass8][kcl2][nt2][lane64] short8 =  32768 B
#define WS1_FRAGS 8192
#define WS2_FRAGS 2048
#define WS_NEED   163840u

typedef __attribute__((ext_vector_type(8))) short short8;
typedef __attribute__((ext_vector_type(4))) float floatx4;

__device__ __forceinline__ short f2bu(float f) {
    union { __hip_bfloat16 h; unsigned short u; } c;
    c.h = __float2bfloat16(f);
    return (short)c.u;
}

// ---- one-time weight convert + swizzle into workspace ----
__global__ __launch_bounds__(256) void cvt_kernel(
    const float* __restrict__ W1, const float* __restrict__ W2,
    short8* __restrict__ ws1, short8* __restrict__ ws2)
{
    int t = blockIdx.x * 256 + threadIdx.x;
    if (t < WS1_FRAGS) {
        int lane = t & 63, ks = (t >> 6) & 3, nt = (t >> 8) & 3, pass = t >> 10;
        int n  = pass * 64 + nt * 16 + (lane & 15);
        int k0 = ks * 32 + ((lane >> 4) << 3);
        short8 v;
#pragma unroll
        for (int j = 0; j < 8; ++j) v[j] = f2bu(W1[(k0 + j) * HID + n]);
        ws1[t] = v;
    } else if (t < WS1_FRAGS + WS2_FRAGS) {
        int t2 = t - WS1_FRAGS;
        int lane = t2 & 63, nt2 = (t2 >> 6) & 1, kcl = (t2 >> 7) & 1, pass = t2 >> 8;
        int kc = pass * 2 + kcl;
        int n  = nt2 * 16 + (lane & 15);
        int k0 = kc * 32 + ((lane >> 4) << 3);
        short8 v;
#pragma unroll
        for (int j = 0; j < 8; ++j) v[j] = f2bu(W2[(k0 + j) * BN + n]);
        ws2[t2] = v;
    }
}

// Block = 4 waves, 8 peds (2/wave, same sequence). B-fragments stream DIRECTLY
// from pre-swizzled global (L1/L2-served, VMEM pipe) -> no fb LDS buffers, no
// main-loop barriers (X1c transpose is wave-private). B-frags hoisted across
// the 2 peds. r8-r12 lesson: 2-ped state can't fit 128 total regs -> stay at
// 2 blocks/CU (launch_bounds(256,2), no spill) and unload the LDS pipe instead.
// Round-1 lesson: keep the per-lane selection recompute (SIMD-parallel, free);
// a cooperative LDS distance buffer serializes on ds_write->read chains.
// Round-2 lesson (TA scatter): the WaT [t][k] layout made each epilogue
// global_load_dwordx4 touch 64 DISTINCT cache lines (16 rows x 2KB stride x
// 4 quadrants) -> ~1 line/cycle through the TA/L1 pipe ≈ +95us of stall that
// shows up as neither VALU nor MFMA. Round-0's Wa[k*16+t] gather is only 4
// lines/instr (16 consecutive floats per quarter-group) -> reverted to it.
// Kept from round 1/2 (validated by round-2 pass, no memory-pipe cost):
//   (c) softmax fully in registers via shfl_xor: one __expf per lane
//       replaces 2x16 libm expf + the LDS LG round-trip.
__global__ __launch_bounds__(256, 2) void fused_pre(
    const float* __restrict__ h_states, const float* __restrict__ last_pos,
    const float* __restrict__ Wpos,     const float* __restrict__ bpos,
    const float* __restrict__ b1,       const float* __restrict__ b2,
    const float* __restrict__ Wa,       const float* __restrict__ ba,
    const short8* __restrict__ ws1,     const short8* __restrict__ ws2,
    float* __restrict__ out)
{
    __shared__ unsigned short X1c[4][2][16][42];   // per-wave, per-ped; pad 42
    __shared__ float X2s[4][512];                  // per-wave X2 [16][32]
    __shared__ float px[N_PED], py[N_PED];
    __shared__ float WS[4][16];                    // total ~20.2 KB

    const int tid = threadIdx.x;
    const int wv  = tid >> 6;
    const int ln  = tid & 63;
    const int q8  = (ln >> 4) << 3;
    const int c15 = ln & 15;
    const int s    = blockIdx.x / 25;
    const int base = s * N_PED;
    const int il0  = (blockIdx.x % 25) * 8 + wv * 2;

    if (tid < N_PED) {
        px[tid] = last_pos[(base + tid) * 2 + 0];
        py[tid] = last_pos[(base + tid) * 2 + 1];
    }
    __syncthreads();                               // the only block barrier

    // ---- per-ped selection (r8-verified, round-0 bitwise) + A-frag build ----
    short8  af[2][4];
    floatx4 c2[2][2] = {};
    for (int pedi = 0; pedi < 2; ++pedi) {
        const int il = il0 + pedi;
        const float xi = px[il], yi = py[il];
        const int mm = c15, qq = ln >> 4;
        int cnt;
        {
            float dxm = __fsub_rn(px[mm], xi), dym = __fsub_rn(py[mm], yi);
            float dm = __fsqrt_rn(__builtin_fmaf(dxm, dxm, __fmul_rn(dym, dym)));
            cnt = 0;
            for (int j = qq * 50; j < qq * 50 + 50; ++j) {
                float dx = __fsub_rn(px[j], xi), dy = __fsub_rn(py[j], yi);
                float dj = __fsqrt_rn(__builtin_fmaf(dx, dx, __fmul_rn(dy, dy)));
                cnt += (dj < dm || (dj == dm && j < mm)) ? 1 : 0;
            }
            cnt += __shfl_xor(cnt, 16, 64);
            cnt += __shfl_xor(cnt, 32, 64);        // lane ln holds rank(ln&15)
        }
        const int sm = cnt;
#pragma unroll
        for (int ks = 0; ks < 2; ++ks) {           // k 0..63: h_sel
            const float* hp = &h_states[(base + sm) * 64 + ks * 32 + q8];
            short8 v;
#pragma unroll
            for (int j = 0; j < 8; ++j) v[j] = f2bu(hp[j]);
            af[pedi][ks] = v;
        }
        const float fx = px[sm] - xi, fy = py[sm] - yi;
#pragma unroll
        for (int ks = 2; ks < 4; ++ks) {           // k 64..127: pos embedding
            int e0 = (ks - 2) * 32 + q8;
            short8 v;
#pragma unroll
            for (int j = 0; j < 8; ++j) {
                float e = fx * Wpos[e0 + j] + fy * Wpos[64 + e0 + j] + bpos[e0 + j];
                v[j] = f2bu(e);
            }
            af[pedi][ks] = v;
        }
    }

    // ---- main loop: 8 passes x 4 n-tiles, no barriers ----
    for (int p = 0; p < 8; ++p) {
#pragma unroll
        for (int ntl = 0; ntl < 4; ++ntl) {
            const int nt = p * 4 + ntl;
            short8 bf[4];                          // B-frags, shared by both peds
#pragma unroll
            for (int ks = 0; ks < 4; ++ks)
                bf[ks] = ws1[p * 1024 + ntl * 256 + ks * 64 + ln];
            const float bb = b1[nt * 16 + c15];
            const int colb = (ntl & 1) * 16 + c15;
#pragma unroll
            for (int pedi = 0; pedi < 2; ++pedi) {
                floatx4 c = {};
#pragma unroll
                for (int ks = 0; ks < 4; ++ks)
                    c = __builtin_amdgcn_mfma_f32_16x16x32_bf16(
                            af[pedi][ks], bf[ks], c, 0, 0, 0);
                // C layout: col = ln&15, row = (ln>>4)*4 + r
#pragma unroll
                for (int r = 0; r < 4; ++r)
                    X1c[wv][pedi][(ln >> 4) * 4 + r][colb] =
                        (unsigned short)f2bu(fmaxf(c[r] + bb, 0.f));
            }
            if (ntl & 1) {                         // 32-col X1 chunks ready
                const int kcl = ntl >> 1;
                short8 w20 = ws2[p * 256 + kcl * 128 + ln];
                short8 w21 = ws2[p * 256 + kcl * 128 + 64 + ln];
#pragma unroll
                for (int pedi = 0; pedi < 2; ++pedi) {
                    short8 a2 = *(const short8*)&X1c[wv][pedi][c15][q8];
                    c2[pedi][0] = __builtin_amdgcn_mfma_f32_16x16x32_bf16(
                            a2, w20, c2[pedi][0], 0, 0, 0);
                    c2[pedi][1] = __builtin_amdgcn_mfma_f32_16x16x32_bf16(
                            a2, w21, c2[pedi][1], 0, 0, 0);
                }
            }
        }
    }

    // ---- epilogue per ped (round-0 logit gather + register softmax) ----
    for (int pedi = 0; pedi < 2; ++pedi) {
#pragma unroll
        for (int nt2 = 0; nt2 < 2; ++nt2) {
            const float bb2 = b2[nt2 * 16 + c15];
#pragma unroll
            for (int r = 0; r < 4; ++r)
                X2s[wv][((ln >> 4) * 4 + r) * 32 + nt2 * 16 + c15] =
                    fmaxf(c2[pedi][nt2][r] + bb2, 0.f);
        }
        float lg;
        {
            const int t = c15, g = ln >> 4;
            lg = 0.f;
            for (int k = g * 128; k < g * 128 + 128; ++k)
                lg += X2s[wv][k] * Wa[k * MAXP + t];
            lg += __shfl_xor(lg, 16, 64);
            lg += __shfl_xor(lg, 32, 64);   // every lane: logit for t = c15
        }
        // softmax over the 16 t's, fully in registers (one __expf per lane)
        const float lgf = lg + ba[c15];
        float mxv = lgf;
        mxv = fmaxf(mxv, __shfl_xor(mxv, 1, 64));
        mxv = fmaxf(mxv, __shfl_xor(mxv, 2, 64));
        mxv = fmaxf(mxv, __shfl_xor(mxv, 4, 64));
        mxv = fmaxf(mxv, __shfl_xor(mxv, 8, 64));
        const float ev = __expf(lgf - mxv);
        float se = ev;
        se += __shfl_xor(se, 1, 64);
        se += __shfl_xor(se, 2, 64);
        se += __shfl_xor(se, 4, 64);
        se += __shfl_xor(se, 8, 64);
        if (ln < 16) WS[wv][ln] = ev / se;
        if (ln < BN) {
            float o = 0.f;
#pragma unroll
            for (int m = 0; m < MAXP; ++m) o += WS[wv][m] * X2s[wv][m * BN + ln];
            out[(base + il0 + pedi) * BN + ln] = o;
        }
    }
}

// Fallback (ws too small): r11-verified LDS-staging version, inline cvt.
__global__ __launch_bounds__(256, 2) void fused_fb(
    const float* __restrict__ h_states, const float* __restrict__ last_pos,
    const float* __restrict__ Wpos,     const float* __restrict__ bpos,
    const float* __restrict__ W1,       const float* __restrict__ b1,
    const float* __restrict__ W2,       const float* __restrict__ b2,
    const float* __restrict__ Wa,       const float* __restrict__ ba,
    float* __restrict__ out)
{
    __shared__ short8 fb1[1024];
    __shared__ short8 fb2[256];
    __shared__ unsigned short X1c[4][16][40];
    __shared__ float X2s[4][512];
    __shared__ float px[N_PED], py[N_PED];
    __shared__ float LG[4][16], WS[4][16];

    const int tid = threadIdx.x;
    const int wv  = tid >> 6;
    const int ln  = tid & 63;
    const int q8  = (ln >> 4) << 3;
    const int c15 = ln & 15;
    const int s    = blockIdx.x / 25;
    const int base = s * N_PED;
    const int il0  = (blockIdx.x % 25) * 8 + wv * 2;

    if (tid < N_PED) {
        px[tid] = last_pos[(base + tid) * 2 + 0];
        py[tid] = last_pos[(base + tid) * 2 + 1];
    }
    __syncthreads();

    short8  af[2][4];
    floatx4 c2[2][2] = {};
    for (int pedi = 0; pedi < 2; ++pedi) {
        const int il = il0 + pedi;
        const float xi = px[il], yi = py[il];
        const int mm = c15, qq = ln >> 4;
        int cnt;
        {
            float dxm = __fsub_rn(px[mm], xi), dym = __fsub_rn(py[mm], yi);
            float dm = __fsqrt_rn(__builtin_fmaf(dxm, dxm, __fmul_rn(dym, dym)));
            cnt = 0;
            for (int j = qq * 50; j < qq * 50 + 50; ++j) {
                float dx = __fsub_rn(px[j], xi), dy = __fsub_rn(py[j], yi);
                float dj = __fsqrt_rn(__builtin_fmaf(dx, dx, __fmul_rn(dy, dy)));
                cnt += (dj < dm || (dj == dm && j < mm)) ? 1 : 0;
            }
            cnt += __shfl_xor(cnt, 16, 64);
            cnt += __shfl_xor(cnt, 32, 64);
        }
        const int sm = cnt;
#pragma unroll
        for (int ks = 0; ks < 2; ++ks) {
            const float* hp = &h_states[(base + sm) * 64 + ks * 32 + q8];
            short8 v;
#pragma unroll
            for (int j = 0; j < 8; ++j) v[j] = f2bu(hp[j]);
            af[pedi][ks] = v;
        }
        const float fx = px[sm] - xi, fy = py[sm] - yi;
#pragma unroll
        for (int ks = 2; ks < 4; ++ks) {
            int e0 = (ks - 2) * 32 + q8;
            short8 v;
#pragma unroll
            for (int j = 0; j < 8; ++j) {
                float e = fx * Wpos[e0 + j] + fy * Wpos[64 + e0 + j] + bpos[e0 + j];
                v[j] = f2bu(e);
            }
            af[pedi][ks] = v;
        }
    }

    for (int p = 0; p < 8; ++p) {
        __syncthreads();
        for (int f = tid; f < 1024; f += 256) {
            int lane = f & 63, ks = (f >> 6) & 3, nt = f >> 8;
            int n  = p * 64 + nt * 16 + (lane & 15);
            int k0 = ks * 32 + ((lane >> 4) << 3);
            short8 v;
#pragma unroll
            for (int j = 0; j < 8; ++j) v[j] = f2bu(W1[(k0 + j) * HID + n]);
            fb1[f] = v;
        }
        {
            int lane = tid & 63, nt2 = (tid >> 6) & 1, kcl = tid >> 7;
            int kc = p * 2 + kcl;
            int n  = nt2 * 16 + (lane & 15);
            int k0 = kc * 32 + ((lane >> 4) << 3);
            short8 v;
#pragma unroll
            for (int j = 0; j < 8; ++j) v[j] = f2bu(W2[(k0 + j) * BN + n]);
            fb2[tid] = v;
        }
        __syncthreads();
#pragma unroll
        for (int pedi = 0; pedi < 2; ++pedi) {
#pragma unroll
            for (int ntl = 0; ntl < 4; ++ntl) {
                const int nt = p * 4 + ntl;
                floatx4 c = {};
#pragma unroll
                for (int ks = 0; ks < 4; ++ks)
                    c = __builtin_amdgcn_mfma_f32_16x16x32_bf16(
                            af[pedi][ks], fb1[ntl * 256 + ks * 64 + ln], c, 0, 0, 0);
                const float bb = b1[nt * 16 + c15];
                const int colb = (ntl & 1) * 16 + c15;
#pragma unroll
                for (int r = 0; r < 4; ++r)
                    X1c[wv][(ln >> 4) * 4 + r][colb] =
                        (unsigned short)f2bu(fmaxf(c[r] + bb, 0.f));
                if (ntl & 1) {
                    const int kcl = ntl >> 1;
                    short8 a2 = *(const short8*)&X1c[wv][c15][q8];
                    c2[pedi][0] = __builtin_amdgcn_mfma_f32_16x16x32_bf16(
                            a2, fb2[kcl * 128 + ln], c2[pedi][0], 0, 0, 0);
                    c2[pedi][1] = __builtin_amdgcn_mfma_f32_16x16x32_bf16(
                            a2, fb2[kcl * 128 + 64 + ln], c2[pedi][1], 0, 0, 0);
                }
            }
        }
    }

    for (int pedi = 0; pedi < 2; ++pedi) {
#pragma unroll
        for (int nt2 = 0; nt2 < 2; ++nt2) {
            const float bb2 = b2[nt2 * 16 + c15];
#pragma unroll
            for (int r = 0; r < 4; ++r)
                X2s[wv][((ln >> 4) * 4 + r) * 32 + nt2 * 16 + c15] =
                    fmaxf(c2[pedi][nt2][r] + bb2, 0.f);
        }
        {
            int t = c15, g = ln >> 4;
            float lg = 0.f;
            for (int k = g * 128; k < g * 128 + 128; ++k)
                lg += X2s[wv][k] * Wa[k * MAXP + t];
            lg += __shfl_xor(lg, 16, 64);
            lg += __shfl_xor(lg, 32, 64);
            if (ln < 16) LG[wv][ln] = lg + ba[ln];
        }
        float mx = -1e30f;
#pragma unroll
        for (int m = 0; m < MAXP; ++m) mx = fmaxf(mx, LG[wv][m]);
        float sum = 0.f;
#pragma unroll
        for (int m = 0; m < MAXP; ++m) sum += expf(LG[wv][m] - mx);
        if (ln < 16) WS[wv][ln] = expf(LG[wv][ln] - mx) / sum;
        if (ln < BN) {
            float o = 0.f;
#pragma unroll
            for (int m = 0; m < MAXP; ++m) o += WS[wv][m] * X2s[wv][m * BN + ln];
            out[(base + il0 + pedi) * BN + ln] = o;
        }
    }
}

extern "C" void kernel_launch(void* const* d_in, const int* in_sizes, int n_in,
                              void* d_out, int out_size, void* d_ws, size_t ws_size,
                              hipStream_t stream) {
    const float* h_states = (const float*)d_in[0];
    const float* last_pos = (const float*)d_in[1];
    const float* Wpos     = (const float*)d_in[2];
    const float* bpos     = (const float*)d_in[3];
    const float* W1       = (const float*)d_in[4];
    const float* b1       = (const float*)d_in[5];
    const float* W2       = (const float*)d_in[6];
    const float* b2       = (const float*)d_in[7];
    const float* Wa       = (const float*)d_in[8];
    const float* ba       = (const float*)d_in[9];
    // d_in[10] seq_start_end, d_in[11] train_or_test: structurally constant, unused

    short8* ws1 = (short8*)d_ws;
    short8* ws2 = ws1 + WS1_FRAGS;
    const int grid = (S_CNT * N_PED) / 8;          // 6250

    if (ws_size >= WS_NEED) {
        cvt_kernel<<<40, 256, 0, stream>>>(W1, W2, ws1, ws2);
        fused_pre<<<grid, 256, 0, stream>>>(
            h_states, last_pos, Wpos, bpos, b1, b2, Wa, ba, ws1, ws2, (float*)d_out);
    } else {
        fused_fb<<<grid, 256, 0, stream>>>(
            h_states, last_pos, Wpos, bpos, W1, b1, W2, b2, Wa, ba, (float*)d_out);
    }
}

// Round 4
// 290.130 us; speedup vs baseline: 1.5236x; 1.0854x over previous
//
#include <hip/hip_runtime.h>
#include <hip/hip_bf16.h>

#define S_CNT 250
#define N_PED 200
#define MAXP  16
#define HID   512
#define BN    32

// d_ws layout: ws1 frags [pass8][ntl4][ks4][lane64] short8 = 131072 B
//              ws2 frags [pass8][kcl2][nt2][lane64] short8 =  32768 B
//              waf frags [kt16][lane64] short8 (W_attn B)  =  16384 B
#define WS1_FRAGS 8192
#define WS2_FRAGS 2048
#define WAF_FRAGS 1024
#define WS_NEED   180224u

typedef __attribute__((ext_vector_type(8))) short short8;
typedef __attribute__((ext_vector_type(4))) float floatx4;

__device__ __forceinline__ short f2bu(float f) {
    union { __hip_bfloat16 h; unsigned short u; } c;
    c.h = __float2bfloat16(f);
    return (short)c.u;
}

// ---- one-time weight convert + swizzle into workspace ----
__global__ __launch_bounds__(256) void cvt_kernel(
    const float* __restrict__ W1, const float* __restrict__ W2,
    const float* __restrict__ Wa,
    short8* __restrict__ ws1, short8* __restrict__ ws2,
    short8* __restrict__ waf)
{
    int t = blockIdx.x * 256 + threadIdx.x;
    if (t < WS1_FRAGS) {
        int lane = t & 63, ks = (t >> 6) & 3, nt = (t >> 8) & 3, pass = t >> 10;
        int n  = pass * 64 + nt * 16 + (lane & 15);
        int k0 = ks * 32 + ((lane >> 4) << 3);
        short8 v;
#pragma unroll
        for (int j = 0; j < 8; ++j) v[j] = f2bu(W1[(k0 + j) * HID + n]);
        ws1[t] = v;
    } else if (t < WS1_FRAGS + WS2_FRAGS) {
        int t2 = t - WS1_FRAGS;
        int lane = t2 & 63, nt2 = (t2 >> 6) & 1, kcl = (t2 >> 7) & 1, pass = t2 >> 8;
        int kc = pass * 2 + kcl;
        int n  = nt2 * 16 + (lane & 15);
        int k0 = kc * 32 + ((lane >> 4) << 3);
        short8 v;
#pragma unroll
        for (int j = 0; j < 8; ++j) v[j] = f2bu(W2[(k0 + j) * BN + n]);
        ws2[t2] = v;
    } else if (t < WS1_FRAGS + WS2_FRAGS + WAF_FRAGS) {
        // B-frag swizzle of W_attn [512][16] for 16x16x32 MFMA:
        // lane holds B[k=k0+j][n=lane&15]
        int t3 = t - (WS1_FRAGS + WS2_FRAGS);
        int lane = t3 & 63, kt = t3 >> 6;
        int n  = lane & 15;
        int k0 = kt * 32 + ((lane >> 4) << 3);
        short8 v;
#pragma unroll
        for (int j = 0; j < 8; ++j) v[j] = f2bu(Wa[(k0 + j) * MAXP + n]);
        waf[t3] = v;
    }
}

// Block = 4 waves, 8 peds (2/wave, same sequence). B-fragments stream DIRECTLY
// from pre-swizzled global (L1/L2-served, VMEM pipe) -> no fb LDS buffers, no
// main-loop barriers (X1c transpose is wave-private). B-frags hoisted across
// the 2 peds. r8-r12 lesson: 2-ped state can't fit 128 total regs -> stay at
// 2 blocks/CU (launch_bounds(256,2), no spill) and unload the LDS pipe instead.
// Round-1 lesson: keep the per-lane selection recompute (SIMD-parallel, free);
// a cooperative LDS distance buffer serializes on ds_write->read chains.
// Round-2 lesson (TA scatter): epilogue loads must not fan out to 64 cache
// lines per instruction; waf fragments below are lane-contiguous like ws2.
// Round-3 verified: register softmax via shfl_xor (one __expf per lane).
// This round: logits via MFMA. The old per-ped 128-iter VALU GEMV
// (~2.6k cyc/wave + 256 scalar Wa loads) is replaced by ONE chain of 16
// mfma_16x16x32_bf16: A rows 0/1 = ped0/ped1 X2 (read from doubled X2s,
// cvt to bf16), rows 2-15 junk; B = pre-swizzled waf; bias in C-init.
__global__ __launch_bounds__(256, 2) void fused_pre(
    const float* __restrict__ h_states, const float* __restrict__ last_pos,
    const float* __restrict__ Wpos,     const float* __restrict__ bpos,
    const float* __restrict__ b1,       const float* __restrict__ b2,
    const float* __restrict__ ba,
    const short8* __restrict__ ws1,     const short8* __restrict__ ws2,
    const short8* __restrict__ waf,
    float* __restrict__ out)
{
    __shared__ unsigned short X1c[4][2][16][42];   // per-wave, per-ped; pad 42
    __shared__ float X2s[4][2][512];               // per-wave, per-ped X2 [16][32]
    __shared__ float px[N_PED], py[N_PED];
    __shared__ float WS[4][16];                    // total ~28.3 KB

    const int tid = threadIdx.x;
    const int wv  = tid >> 6;
    const int ln  = tid & 63;
    const int q8  = (ln >> 4) << 3;
    const int c15 = ln & 15;
    const int s    = blockIdx.x / 25;
    const int base = s * N_PED;
    const int il0  = (blockIdx.x % 25) * 8 + wv * 2;

    if (tid < N_PED) {
        px[tid] = last_pos[(base + tid) * 2 + 0];
        py[tid] = last_pos[(base + tid) * 2 + 1];
    }
    __syncthreads();                               // the only block barrier

    // ---- per-ped selection (r8-verified, round-0 bitwise) + A-frag build ----
    short8  af[2][4];
    floatx4 c2[2][2] = {};
    for (int pedi = 0; pedi < 2; ++pedi) {
        const int il = il0 + pedi;
        const float xi = px[il], yi = py[il];
        const int mm = c15, qq = ln >> 4;
        int cnt;
        {
            float dxm = __fsub_rn(px[mm], xi), dym = __fsub_rn(py[mm], yi);
            float dm = __fsqrt_rn(__builtin_fmaf(dxm, dxm, __fmul_rn(dym, dym)));
            cnt = 0;
            for (int j = qq * 50; j < qq * 50 + 50; ++j) {
                float dx = __fsub_rn(px[j], xi), dy = __fsub_rn(py[j], yi);
                float dj = __fsqrt_rn(__builtin_fmaf(dx, dx, __fmul_rn(dy, dy)));
                cnt += (dj < dm || (dj == dm && j < mm)) ? 1 : 0;
            }
            cnt += __shfl_xor(cnt, 16, 64);
            cnt += __shfl_xor(cnt, 32, 64);        // lane ln holds rank(ln&15)
        }
        const int sm = cnt;
#pragma unroll
        for (int ks = 0; ks < 2; ++ks) {           // k 0..63: h_sel
            const float* hp = &h_states[(base + sm) * 64 + ks * 32 + q8];
            short8 v;
#pragma unroll
            for (int j = 0; j < 8; ++j) v[j] = f2bu(hp[j]);
            af[pedi][ks] = v;
        }
        const float fx = px[sm] - xi, fy = py[sm] - yi;
#pragma unroll
        for (int ks = 2; ks < 4; ++ks) {           // k 64..127: pos embedding
            int e0 = (ks - 2) * 32 + q8;
            short8 v;
#pragma unroll
            for (int j = 0; j < 8; ++j) {
                float e = fx * Wpos[e0 + j] + fy * Wpos[64 + e0 + j] + bpos[e0 + j];
                v[j] = f2bu(e);
            }
            af[pedi][ks] = v;
        }
    }

    // ---- main loop: 8 passes x 4 n-tiles, no barriers ----
    for (int p = 0; p < 8; ++p) {
#pragma unroll
        for (int ntl = 0; ntl < 4; ++ntl) {
            const int nt = p * 4 + ntl;
            short8 bf[4];                          // B-frags, shared by both peds
#pragma unroll
            for (int ks = 0; ks < 4; ++ks)
                bf[ks] = ws1[p * 1024 + ntl * 256 + ks * 64 + ln];
            const float bb = b1[nt * 16 + c15];
            const int colb = (ntl & 1) * 16 + c15;
#pragma unroll
            for (int pedi = 0; pedi < 2; ++pedi) {
                floatx4 c = {};
#pragma unroll
                for (int ks = 0; ks < 4; ++ks)
                    c = __builtin_amdgcn_mfma_f32_16x16x32_bf16(
                            af[pedi][ks], bf[ks], c, 0, 0, 0);
                // C layout: col = ln&15, row = (ln>>4)*4 + r
#pragma unroll
                for (int r = 0; r < 4; ++r)
                    X1c[wv][pedi][(ln >> 4) * 4 + r][colb] =
                        (unsigned short)f2bu(fmaxf(c[r] + bb, 0.f));
            }
            if (ntl & 1) {                         // 32-col X1 chunks ready
                const int kcl = ntl >> 1;
                short8 w20 = ws2[p * 256 + kcl * 128 + ln];
                short8 w21 = ws2[p * 256 + kcl * 128 + 64 + ln];
#pragma unroll
                for (int pedi = 0; pedi < 2; ++pedi) {
                    short8 a2 = *(const short8*)&X1c[wv][pedi][c15][q8];
                    c2[pedi][0] = __builtin_amdgcn_mfma_f32_16x16x32_bf16(
                            a2, w20, c2[pedi][0], 0, 0, 0);
                    c2[pedi][1] = __builtin_amdgcn_mfma_f32_16x16x32_bf16(
                            a2, w21, c2[pedi][1], 0, 0, 0);
                }
            }
        }
    }

    // ---- epilogue: X2 (f32) for both peds to LDS ----
#pragma unroll
    for (int pedi = 0; pedi < 2; ++pedi)
#pragma unroll
        for (int nt2 = 0; nt2 < 2; ++nt2) {
            const float bb2 = b2[nt2 * 16 + c15];
#pragma unroll
            for (int r = 0; r < 4; ++r)
                X2s[wv][pedi][((ln >> 4) * 4 + r) * 32 + nt2 * 16 + c15] =
                    fmaxf(c2[pedi][nt2][r] + bb2, 0.f);
        }

    // ---- logits via MFMA: D[row][t], row0=ped0, row1=ped1, rows 2-15 junk.
    // A-frag: lane l supplies A[row=l&15][k=kt*32+(l>>4)*8+j]; only the
    // ped parity matters for the used rows -> read X2s[wv][c15&1].
    floatx4 cl;
    {
        const float bav = ba[c15];                 // bias folded into C-init
        cl[0] = bav; cl[1] = bav; cl[2] = 0.f; cl[3] = 0.f;
    }
    const float* xbase = &X2s[wv][c15 & 1][q8];
#pragma unroll
    for (int kt = 0; kt < 16; ++kt) {
        const float* xp = xbase + kt * 32;
        short8 a;
#pragma unroll
        for (int j = 0; j < 8; ++j) a[j] = f2bu(xp[j]);
        cl = __builtin_amdgcn_mfma_f32_16x16x32_bf16(a, waf[kt * 64 + ln], cl, 0, 0, 0);
    }
    // C layout: col=ln&15, row=(ln>>4)*4+r -> ped0 logits in cl[0] of lanes
    // 0-15, ped1 in cl[1]. Broadcast logit[t=c15] to every lane.
    const float lg0 = __shfl(cl[0], c15, 64);
    const float lg1 = __shfl(cl[1], c15, 64);

#pragma unroll
    for (int pedi = 0; pedi < 2; ++pedi) {
        // softmax over the 16 t's, fully in registers (one __expf per lane)
        const float lgf = pedi ? lg1 : lg0;        // bias already included
        float mxv = lgf;
        mxv = fmaxf(mxv, __shfl_xor(mxv, 1, 64));
        mxv = fmaxf(mxv, __shfl_xor(mxv, 2, 64));
        mxv = fmaxf(mxv, __shfl_xor(mxv, 4, 64));
        mxv = fmaxf(mxv, __shfl_xor(mxv, 8, 64));
        const float ev = __expf(lgf - mxv);
        float se = ev;
        se += __shfl_xor(se, 1, 64);
        se += __shfl_xor(se, 2, 64);
        se += __shfl_xor(se, 4, 64);
        se += __shfl_xor(se, 8, 64);
        if (ln < 16) WS[wv][ln] = ev / se;
        if (ln < BN) {
            float o = 0.f;
#pragma unroll
            for (int m = 0; m < MAXP; ++m)
                o += WS[wv][m] * X2s[wv][pedi][m * BN + ln];
            out[(base + il0 + pedi) * BN + ln] = o;
        }
    }
}

// Fallback (ws too small): r11-verified LDS-staging version, inline cvt.
__global__ __launch_bounds__(256, 2) void fused_fb(
    const float* __restrict__ h_states, const float* __restrict__ last_pos,
    const float* __restrict__ Wpos,     const float* __restrict__ bpos,
    const float* __restrict__ W1,       const float* __restrict__ b1,
    const float* __restrict__ W2,       const float* __restrict__ b2,
    const float* __restrict__ Wa,       const float* __restrict__ ba,
    float* __restrict__ out)
{
    __shared__ short8 fb1[1024];
    __shared__ short8 fb2[256];
    __shared__ unsigned short X1c[4][16][40];
    __shared__ float X2s[4][512];
    __shared__ float px[N_PED], py[N_PED];
    __shared__ float LG[4][16], WS[4][16];

    const int tid = threadIdx.x;
    const int wv  = tid >> 6;
    const int ln  = tid & 63;
    const int q8  = (ln >> 4) << 3;
    const int c15 = ln & 15;
    const int s    = blockIdx.x / 25;
    const int base = s * N_PED;
    const int il0  = (blockIdx.x % 25) * 8 + wv * 2;

    if (tid < N_PED) {
        px[tid] = last_pos[(base + tid) * 2 + 0];
        py[tid] = last_pos[(base + tid) * 2 + 1];
    }
    __syncthreads();

    short8  af[2][4];
    floatx4 c2[2][2] = {};
    for (int pedi = 0; pedi < 2; ++pedi) {
        const int il = il0 + pedi;
        const float xi = px[il], yi = py[il];
        const int mm = c15, qq = ln >> 4;
        int cnt;
        {
            float dxm = __fsub_rn(px[mm], xi), dym = __fsub_rn(py[mm], yi);
            float dm = __fsqrt_rn(__builtin_fmaf(dxm, dxm, __fmul_rn(dym, dym)));
            cnt = 0;
            for (int j = qq * 50; j < qq * 50 + 50; ++j) {
                float dx = __fsub_rn(px[j], xi), dy = __fsub_rn(py[j], yi);
                float dj = __fsqrt_rn(__builtin_fmaf(dx, dx, __fmul_rn(dy, dy)));
                cnt += (dj < dm || (dj == dm && j < mm)) ? 1 : 0;
            }
            cnt += __shfl_xor(cnt, 16, 64);
            cnt += __shfl_xor(cnt, 32, 64);
        }
        const int sm = cnt;
#pragma unroll
        for (int ks = 0; ks < 2; ++ks) {
            const float* hp = &h_states[(base + sm) * 64 + ks * 32 + q8];
            short8 v;
#pragma unroll
            for (int j = 0; j < 8; ++j) v[j] = f2bu(hp[j]);
            af[pedi][ks] = v;
        }
        const float fx = px[sm] - xi, fy = py[sm] - yi;
#pragma unroll
        for (int ks = 2; ks < 4; ++ks) {
            int e0 = (ks - 2) * 32 + q8;
            short8 v;
#pragma unroll
            for (int j = 0; j < 8; ++j) {
                float e = fx * Wpos[e0 + j] + fy * Wpos[64 + e0 + j] + bpos[e0 + j];
                v[j] = f2bu(e);
            }
            af[pedi][ks] = v;
        }
    }

    for (int p = 0; p < 8; ++p) {
        __syncthreads();
        for (int f = tid; f < 1024; f += 256) {
            int lane = f & 63, ks = (f >> 6) & 3, nt = f >> 8;
            int n  = p * 64 + nt * 16 + (lane & 15);
            int k0 = ks * 32 + ((lane >> 4) << 3);
            short8 v;
#pragma unroll
            for (int j = 0; j < 8; ++j) v[j] = f2bu(W1[(k0 + j) * HID + n]);
            fb1[f] = v;
        }
        {
            int lane = tid & 63, nt2 = (tid >> 6) & 1, kcl = tid >> 7;
            int kc = p * 2 + kcl;
            int n  = nt2 * 16 + (lane & 15);
            int k0 = kc * 32 + ((lane >> 4) << 3);
            short8 v;
#pragma unroll
            for (int j = 0; j < 8; ++j) v[j] = f2bu(W2[(k0 + j) * BN + n]);
            fb2[tid] = v;
        }
        __syncthreads();
#pragma unroll
        for (int pedi = 0; pedi < 2; ++pedi) {
#pragma unroll
            for (int ntl = 0; ntl < 4; ++ntl) {
                const int nt = p * 4 + ntl;
                floatx4 c = {};
#pragma unroll
                for (int ks = 0; ks < 4; ++ks)
                    c = __builtin_amdgcn_mfma_f32_16x16x32_bf16(
                            af[pedi][ks], fb1[ntl * 256 + ks * 64 + ln], c, 0, 0, 0);
                const float bb = b1[nt * 16 + c15];
                const int colb = (ntl & 1) * 16 + c15;
#pragma unroll
                for (int r = 0; r < 4; ++r)
                    X1c[wv][(ln >> 4) * 4 + r][colb] =
                        (unsigned short)f2bu(fmaxf(c[r] + bb, 0.f));
                if (ntl & 1) {
                    const int kcl = ntl >> 1;
                    short8 a2 = *(const short8*)&X1c[wv][c15][q8];
                    c2[pedi][0] = __builtin_amdgcn_mfma_f32_16x16x32_bf16(
                            a2, fb2[kcl * 128 + ln], c2[pedi][0], 0, 0, 0);
                    c2[pedi][1] = __builtin_amdgcn_mfma_f32_16x16x32_bf16(
                            a2, fb2[kcl * 128 + 64 + ln], c2[pedi][1], 0, 0, 0);
                }
            }
        }
    }

    for (int pedi = 0; pedi < 2; ++pedi) {
#pragma unroll
        for (int nt2 = 0; nt2 < 2; ++nt2) {
            const float bb2 = b2[nt2 * 16 + c15];
#pragma unroll
            for (int r = 0; r < 4; ++r)
                X2s[wv][((ln >> 4) * 4 + r) * 32 + nt2 * 16 + c15] =
                    fmaxf(c2[pedi][nt2][r] + bb2, 0.f);
        }
        {
            int t = c15, g = ln >> 4;
            float lg = 0.f;
            for (int k = g * 128; k < g * 128 + 128; ++k)
                lg += X2s[wv][k] * Wa[k * MAXP + t];
            lg += __shfl_xor(lg, 16, 64);
            lg += __shfl_xor(lg, 32, 64);
            if (ln < 16) LG[wv][ln] = lg + ba[ln];
        }
        float mx = -1e30f;
#pragma unroll
        for (int m = 0; m < MAXP; ++m) mx = fmaxf(mx, LG[wv][m]);
        float sum = 0.f;
#pragma unroll
        for (int m = 0; m < MAXP; ++m) sum += expf(LG[wv][m] - mx);
        if (ln < 16) WS[wv][ln] = expf(LG[wv][ln] - mx) / sum;
        if (ln < BN) {
            float o = 0.f;
#pragma unroll
            for (int m = 0; m < MAXP; ++m) o += WS[wv][m] * X2s[wv][m * BN + ln];
            out[(base + il0 + pedi) * BN + ln] = o;
        }
    }
}

extern "C" void kernel_launch(void* const* d_in, const int* in_sizes, int n_in,
                              void* d_out, int out_size, void* d_ws, size_t ws_size,
                              hipStream_t stream) {
    const float* h_states = (const float*)d_in[0];
    const float* last_pos = (const float*)d_in[1];
    const float* Wpos     = (const float*)d_in[2];
    const float* bpos     = (const float*)d_in[3];
    const float* W1       = (const float*)d_in[4];
    const float* b1       = (const float*)d_in[5];
    const float* W2       = (const float*)d_in[6];
    const float* b2       = (const float*)d_in[7];
    const float* Wa       = (const float*)d_in[8];
    const float* ba       = (const float*)d_in[9];
    // d_in[10] seq_start_end, d_in[11] train_or_test: structurally constant, unused

    short8* ws1 = (short8*)d_ws;
    short8* ws2 = ws1 + WS1_FRAGS;
    short8* waf = ws2 + WS2_FRAGS;
    const int grid = (S_CNT * N_PED) / 8;          // 6250

    if (ws_size >= WS_NEED) {
        cvt_kernel<<<44, 256, 0, stream>>>(W1, W2, Wa, ws1, ws2, waf);
        fused_pre<<<grid, 256, 0, stream>>>(
            h_states, last_pos, Wpos, bpos, b1, b2, ba, ws1, ws2, waf, (float*)d_out);
    } else {
        fused_fb<<<grid, 256, 0, stream>>>(
            h_states, last_pos, Wpos, bpos, W1, b1, W2, b2, Wa, ba, (float*)d_out);
    }
}